// Round 8
// baseline (203.540 us; speedup 1.0000x reference)
//
#include <hip/hip_runtime.h>
#include <hip/hip_bf16.h>

// MultiHeadSelfAttention: B=2, S=2048, D=1024, H=16, DK=64
// R8: revert to R6 everywhere except attn: K-tile 128 (2x 64 sub-tiles per
//     double-buffered iteration -> 16 barriers instead of 32; the vmcnt(0)
//     barrier drain was ~2/3 of attn time at 1 wave/SIMD), plus R7's 3-op
//     bf16 pack (u+0x8000 + v_perm). No VGPR cap (R7's spill regression).

using bf16 = __hip_bfloat16;
typedef __attribute__((ext_vector_type(8))) short bf16x8;   // 8 bf16 = 4 VGPRs
typedef __attribute__((ext_vector_type(4))) float f32x4;

#define QSCALE 0.18033688011112042f   // (1/sqrt(64)) * log2(e)

static __device__ __forceinline__ f32x4 mfma_bf16(bf16x8 a, bf16x8 b, f32x4 c) {
    return __builtin_amdgcn_mfma_f32_16x16x32_bf16(a, b, c, 0, 0, 0);
}

static __device__ __forceinline__ void gld_lds16(const void* g, void* s) {
    __builtin_amdgcn_global_load_lds(
        (const __attribute__((address_space(1))) unsigned int*)g,
        (__attribute__((address_space(3))) unsigned int*)s,
        16, 0, 0);
}

// pack two fp32 -> bf16x2 (round-half-up), 3 VALU ops; valid for p >= 0
static __device__ __forceinline__ unsigned int pk_bf16(float lo, float hi) {
    unsigned int ul = __builtin_bit_cast(unsigned int, lo) + 0x8000u;
    unsigned int uh = __builtin_bit_cast(unsigned int, hi) + 0x8000u;
    return __builtin_amdgcn_perm(uh, ul, 0x07060302u);   // {ul.hi16, uh.hi16}
}

// ---------------- fused prep: cast x + transpose both weights ----------------
__global__ void prep_kernel(const float* __restrict__ x, bf16* __restrict__ xb,
                            const float* __restrict__ wqkv, bf16* __restrict__ wqkvT,
                            const float* __restrict__ wo, bf16* __restrict__ woT) {
    __shared__ float tile[32][33];
    int blk = blockIdx.x;
    if (blk < 4096) {
        int i = blk * 256 + threadIdx.x;
        float4 f = reinterpret_cast<const float4*>(x)[i];
        xb[4*i+0] = __float2bfloat16(f.x);
        xb[4*i+1] = __float2bfloat16(f.y);
        xb[4*i+2] = __float2bfloat16(f.z);
        xb[4*i+3] = __float2bfloat16(f.w);
        return;
    }
    const float* in; bf16* out; int R, C, bx, by;
    if (blk < 7168) {
        int idx = blk - 4096; in = wqkv; out = wqkvT; R = 1024; C = 3072;
        bx = idx % 96; by = idx / 96;
    } else {
        int idx = blk - 7168; in = wo; out = woT; R = 1024; C = 1024;
        bx = idx & 31; by = idx >> 5;
    }
    int c0 = bx * 32, r0 = by * 32;
    int xo = threadIdx.x & 31, yo = threadIdx.x >> 5;   // (32,8)
#pragma unroll
    for (int i = 0; i < 32; i += 8) tile[yo + i][xo] = in[(size_t)(r0 + yo + i) * C + c0 + xo];
    __syncthreads();
#pragma unroll
    for (int i = 0; i < 32; i += 8)
        out[(size_t)(c0 + yo + i) * R + r0 + xo] = __float2bfloat16(tile[xo][yo + i]);
}

// ---------------- transpose V + dual-slice kpos permutation ----------------
__global__ void transpose_v_kernel(const bf16* __restrict__ in, bf16* __restrict__ out) {
    __shared__ bf16 t[64][72];
    const int bh = blockIdx.y, s0 = blockIdx.x * 64;
    const int r = threadIdx.x >> 2, c16 = (threadIdx.x & 3) * 16;
    const uint4* src = (const uint4*)(in + ((size_t)bh * 2048 + s0 + r) * 64 + c16);
    uint4 a0 = src[0], a1 = src[1];
    *(uint4*)&t[r][c16] = a0;
    *(uint4*)&t[r][c16 + 8] = a1;
    __syncthreads();
    bf16 tmp[16];
#pragma unroll
    for (int ii = 0; ii < 16; ++ii) {
        int i = c16 + ii;
        int a = i >> 5, rem = i & 31, q = rem >> 3, jj = rem & 7;
        int sp = a * 32 + q * 4 + (jj < 4 ? jj : 16 + jj - 4);
        tmp[ii] = t[sp][r];
    }
    uint4* dst = (uint4*)(out + ((size_t)bh * 64 + r) * 2048 + s0 + c16);
    dst[0] = ((uint4*)tmp)[0];
    dst[1] = ((uint4*)tmp)[1];
}

// ---------------- GEMM: C[M,N] = A[M,K] @ Bt[N,K]^T  (bf16 in, fp32 acc) ----------------
template <int EPI, int TM, int MINW>
__global__ __launch_bounds__(256, MINW)
void gemm_bt_kernel(const bf16* __restrict__ A, const bf16* __restrict__ Bt,
                    int M, int N, int K,
                    const float* __restrict__ bias, const float* __restrict__ gamma,
                    bf16* __restrict__ Qout, bf16* __restrict__ Kout, bf16* __restrict__ Vout,
                    float* __restrict__ Cout) {
    constexpr int MI = TM / 32;
    constexpr int CA = TM / 32;
    __shared__ __align__(16) bf16 As[TM * 64];
    __shared__ __align__(16) bf16 Bs[128 * 64];

    const int tid  = threadIdx.x;
    const int wave = tid >> 6, lane = tid & 63;
    const int quad = lane >> 4, l16 = lane & 15;
    const int wr = wave >> 1, wc = wave & 1;
    const int bm = blockIdx.y, bn = blockIdx.x;

    f32x4 acc[MI][4] = {};

    const int crow = lane >> 3;
    const int sblk = (lane & 7) ^ (crow & 7);
    const bf16* gA[CA]; const bf16* gB[4]; bf16* lA[CA]; bf16* lB[4];
#pragma unroll
    for (int c = 0; c < CA; ++c) {
        int ch = wave * CA + c;
        gA[c] = A + (size_t)(bm * TM + ch * 8 + crow) * K + sblk * 8;
        lA[c] = As + ch * 512 + lane * 8;
    }
#pragma unroll
    for (int c = 0; c < 4; ++c) {
        int ch = wave * 4 + c;
        gB[c] = Bt + (size_t)(bn * 128 + ch * 8 + crow) * K + sblk * 8;
        lB[c] = Bs + ch * 512 + lane * 8;
    }
    const int xr = l16 & 7;

    for (int k0 = 0; k0 < K; k0 += 64) {
#pragma unroll
        for (int c = 0; c < CA; ++c) gld_lds16(gA[c] + k0, lA[c]);
#pragma unroll
        for (int c = 0; c < 4; ++c) gld_lds16(gB[c] + k0, lB[c]);
        __syncthreads();
#pragma unroll
        for (int ks = 0; ks < 2; ++ks) {
            bf16x8 af[MI], bfr[4];
#pragma unroll
            for (int mi = 0; mi < MI; ++mi)
                af[mi] = *(const bf16x8*)(As + (wr * (TM/2) + mi * 16 + l16) * 64 + ((4 * ks + quad) ^ xr) * 8);
#pragma unroll
            for (int ni = 0; ni < 4; ++ni)
                bfr[ni] = *(const bf16x8*)(Bs + (wc * 64 + ni * 16 + l16) * 64 + ((4 * ks + quad) ^ xr) * 8);
#pragma unroll
            for (int mi = 0; mi < MI; ++mi)
#pragma unroll
                for (int ni = 0; ni < 4; ++ni)
                    acc[mi][ni] = mfma_bf16(af[mi], bfr[ni], acc[mi][ni]);
        }
        __syncthreads();
    }

#pragma unroll
    for (int mi = 0; mi < MI; ++mi) {
#pragma unroll
        for (int ni = 0; ni < 4; ++ni) {
#pragma unroll
            for (int r = 0; r < 4; ++r) {
                int row = bm * TM + wr * (TM/2) + mi * 16 + quad * 4 + r;
                int col = bn * 128 + wc * 64 + ni * 16 + l16;
                float v = acc[mi][ni][r];
                if (EPI == 0) {
                    v += bias[col];
                    int h = col / 192;
                    int rr = col - h * 192;
                    int which = rr >> 6, dk = rr & 63;
                    int b = row >> 11, s = row & 2047;   // S = 2048
                    size_t bh = (size_t)b * 16 + h;
                    if (which == 0) {
                        Qout[(bh * 2048 + s) * 64 + dk] = __float2bfloat16(v * QSCALE);
                    } else if (which == 1) {
                        Kout[(bh * 2048 + s) * 64 + dk] = __float2bfloat16(v);
                    } else {
                        Vout[(bh * 2048 + s) * 64 + dk] = __float2bfloat16(v);
                    }
                } else {
                    float o = (gamma[col] + 1.0f) * (v + bias[col]);
                    Cout[(size_t)row * N + col] = o;
                }
            }
        }
    }
}

// ---------------- flash attention: 2 waves x 64 q-rows, K-tile 128, dbuf ----------------
// grid (S/128, B*H), block 128. Wave w owns q rows [q0+64w, +64) as m=0..3.
// Each buffered iteration covers 128 k-positions as two 64-sub-tiles; one
// barrier per 128-k iteration (16 total).
__global__ __launch_bounds__(128, 1)
void attn_kernel(const bf16* __restrict__ Qb, const bf16* __restrict__ Kb,
                 const bf16* __restrict__ Vtp, const int* __restrict__ mask,
                 bf16* __restrict__ Aout) {
    __shared__ __align__(16) bf16 Ks[2][2][64 * 64];   // [buf][sub][kpos][dk]
    __shared__ __align__(16) bf16 Vs[2][2][64 * 64];   // [buf][sub][dk][kpos']
    __shared__ float Biass[2][128];

    const int bh = blockIdx.y;
    const int b = bh >> 4, h = bh & 15;
    const int q0 = blockIdx.x * 128;
    const int tid = threadIdx.x;
    const int wave = tid >> 6, lane = tid & 63;
    const int quad = lane >> 4, l16 = lane & 15;
    const int xr = l16 & 7;

    // Q fragments: wave owns q rows q0 + wave*64 + m*16 + l16
    bf16x8 aq[4][2];
#pragma unroll
    for (int m = 0; m < 4; ++m) {
        const bf16* qp = Qb + ((size_t)bh * 2048 + q0 + wave * 64 + m * 16 + l16) * 64;
        aq[m][0] = *(const bf16x8*)(qp + quad * 8);
        aq[m][1] = *(const bf16x8*)(qp + 32 + quad * 8);
    }

    bf16x8 ones;
#pragma unroll
    for (int j = 0; j < 8; ++j) ones[j] = (short)0x3F80;   // bf16 1.0

    f32x4 O[4][4] = {};
    f32x4 Lacc[4] = {};

    // DMA staging: inst c stages 16 rows (2 waves x 8); lane l -> row +(l>>3),
    // phys 16B-block l&7 holds source block (l&7)^(l>>3).
    const int r8 = lane >> 3, b8 = lane & 7;
    const int srcb = b8 ^ r8;
    const bf16* gK = Kb  + ((size_t)bh * 2048 + wave * 8 + r8) * 64 + srcb * 8;
    const bf16* gV = Vtp + ((size_t)bh * 64 + wave * 8 + r8) * 2048 + srcb * 8;

    // LDS write targets (per buf, per sub-tile, per c)
    auto lK = [&](int p, int s, int c) {
        return Ks[p][s] + c * 1024 + wave * 512 + lane * 8;
    };
    auto lV = [&](int p, int s, int c) {
        return Vs[p][s] + c * 1024 + wave * 512 + lane * 8;
    };

    // prologue: DMA 128-k tile 0 -> buf0; bias0; prefetch mask for tile 1
    int mreg = 0;
#pragma unroll
    for (int s = 0; s < 2; ++s)
#pragma unroll
        for (int c = 0; c < 4; ++c) {
            gld_lds16(gK + (size_t)(s * 64) * 64 + c * 1024, lK(0, s, c));
            gld_lds16(gV + s * 64 + (size_t)c * 32768, lV(0, s, c));
        }
    Biass[0][wave * 64 + lane] = mask[b * 2048 + wave * 64 + lane] ? -24.0f : -1e30f;
    mreg = mask[b * 2048 + 128 + wave * 64 + lane];

    for (int kt = 0; kt < 16; ++kt) {
        __syncthreads();   // buf[cur] DMA + bias landed; prior reads of buf[nxt] done
        const int cur = kt & 1, nxt = cur ^ 1;

        if (kt + 1 < 16) {
#pragma unroll
            for (int s = 0; s < 2; ++s)
#pragma unroll
                for (int c = 0; c < 4; ++c) {
                    gld_lds16(gK + (size_t)((kt + 1) * 128 + s * 64) * 64 + c * 1024, lK(nxt, s, c));
                    gld_lds16(gV + (kt + 1) * 128 + s * 64 + (size_t)c * 32768, lV(nxt, s, c));
                }
            Biass[nxt][wave * 64 + lane] = mreg ? -24.0f : -1e30f;
        }
        if (kt + 2 < 16) mreg = mask[b * 2048 + (kt + 2) * 128 + wave * 64 + lane];

#pragma unroll
        for (int s = 0; s < 2; ++s) {
            const bf16* Ksc = Ks[cur][s];
            const bf16* Vsc = Vs[cur][s];
            const float* Bic = &Biass[cur][s * 64];

            f32x4 bias4[4];
            bf16x8 bk[4][2];
#pragma unroll
            for (int kt4 = 0; kt4 < 4; ++kt4) {
                bias4[kt4] = *(const f32x4*)(Bic + kt4 * 16 + quad * 4);
                const bf16* kp = Ksc + (kt4 * 16 + l16) * 64;
                bk[kt4][0] = *(const bf16x8*)(kp + (quad ^ xr) * 8);
                bk[kt4][1] = *(const bf16x8*)(kp + ((quad + 4) ^ xr) * 8);
            }
            bf16x8 bv8[2][4];
#pragma unroll
            for (int a = 0; a < 2; ++a)
#pragma unroll
                for (int nt = 0; nt < 4; ++nt)
                    bv8[a][nt] = *(const bf16x8*)(Vsc + (nt * 16 + l16) * 64 + ((a * 4 + quad) ^ xr) * 8);

#pragma unroll
            for (int m = 0; m < 4; ++m) {
                f32x4 sv[4];
#pragma unroll
                for (int kt4 = 0; kt4 < 4; ++kt4) {
                    f32x4 c = {0.f, 0.f, 0.f, 0.f};
                    c = mfma_bf16(bk[kt4][0], aq[m][0], c);
                    c = mfma_bf16(bk[kt4][1], aq[m][1], c);
                    sv[kt4] = c;
                }
                float p[4][4];
#pragma unroll
                for (int kt4 = 0; kt4 < 4; ++kt4)
#pragma unroll
                    for (int r = 0; r < 4; ++r)
                        p[kt4][r] = __builtin_amdgcn_exp2f(sv[kt4][r] + bias4[kt4][r]);

#pragma unroll
                for (int a = 0; a < 2; ++a) {
                    uint4 uv;
                    uv.x = pk_bf16(p[2*a][0],   p[2*a][1]);
                    uv.y = pk_bf16(p[2*a][2],   p[2*a][3]);
                    uv.z = pk_bf16(p[2*a+1][0], p[2*a+1][1]);
                    uv.w = pk_bf16(p[2*a+1][2], p[2*a+1][3]);
                    bf16x8 pa = __builtin_bit_cast(bf16x8, uv);
                    Lacc[m] = mfma_bf16(pa, ones, Lacc[m]);
#pragma unroll
                    for (int nt = 0; nt < 4; ++nt)
                        O[m][nt] = mfma_bf16(pa, bv8[a][nt], O[m][nt]);
                }
            }
        }
    }

    // epilogue: O / l
#pragma unroll
    for (int m = 0; m < 4; ++m) {
        float inv[4];
#pragma unroll
        for (int r = 0; r < 4; ++r) inv[r] = __builtin_amdgcn_rcpf(Lacc[m][r]);
#pragma unroll
        for (int nt = 0; nt < 4; ++nt) {
#pragma unroll
            for (int r = 0; r < 4; ++r) {
                int row = q0 + wave * 64 + m * 16 + quad * 4 + r;
                Aout[((size_t)b * 2048 + row) * 1024 + h * 64 + nt * 16 + l16] =
                    __float2bfloat16(O[m][nt][r] * inv[r]);
            }
        }
    }
}

// ---------------- launcher ----------------
extern "C" void kernel_launch(void* const* d_in, const int* in_sizes, int n_in,
                              void* d_out, int out_size, void* d_ws, size_t ws_size,
                              hipStream_t stream) {
    const float* x     = (const float*)d_in[0];
    const float* gamma = (const float*)d_in[1];
    const int*   mask  = (const int*)d_in[2];
    const float* wqkv  = (const float*)d_in[3];
    const float* bqkv  = (const float*)d_in[4];
    const float* wo    = (const float*)d_in[5];
    const float* bo    = (const float*)d_in[6];
    float* out = (float*)d_out;

    char* ws = (char*)d_ws;
    const size_t MB = 1u << 20;
    bf16* xb    = (bf16*)(ws);            //  8 MB
    bf16* wqkvT = (bf16*)(ws + 8 * MB);   //  6 MB
    bf16* woT   = (bf16*)(ws + 14 * MB);  //  2 MB
    bf16* Qb    = (bf16*)(ws + 16 * MB);  //  8 MB
    bf16* Kb    = (bf16*)(ws + 24 * MB);  //  8 MB
    bf16* Vt    = (bf16*)(ws + 32 * MB);  //  8 MB (transposed + kpos-permuted)
    bf16* Vtmp  = (bf16*)(ws + 40 * MB);  //  8 MB (dead after transpose)
    bf16* attn  = (bf16*)(ws + 40 * MB);  //  8 MB (reuses Vtmp slot)

    prep_kernel<<<8192, 256, 0, stream>>>(x, xb, wqkv, wqkvT, wo, woT);

    gemm_bt_kernel<0, 128, 3><<<dim3(24, 32), 256, 0, stream>>>(
        xb, wqkvT, 4096, 3072, 1024, bqkv, nullptr, Qb, Kb, Vtmp, nullptr);

    transpose_v_kernel<<<dim3(32, 32), 256, 0, stream>>>(Vtmp, Vt);

    attn_kernel<<<dim3(16, 32), 128, 0, stream>>>(Qb, Kb, Vt, mask, attn);

    gemm_bt_kernel<1, 64, 4><<<dim3(8, 64), 256, 0, stream>>>(
        attn, woT, 4096, 1024, 1024, bo, gamma, nullptr, nullptr, nullptr, out);
}

// Round 10
// 191.865 us; speedup vs baseline: 1.0608x; 1.0608x over previous
//
#include <hip/hip_runtime.h>
#include <hip/hip_bf16.h>

// MultiHeadSelfAttention: B=2, S=2048, D=1024, H=16, DK=64
// R10: R9 with two V-path fixes:
//   (1) V^T store used bm*128 as s (includes batch offset) -> (bm&15)*128.
//   (2) missing __syncthreads() before reusing As/Bs LDS as the transpose
//       buffer (race with other waves' final MFMA fragment reads).

using bf16 = __hip_bfloat16;
typedef __attribute__((ext_vector_type(8))) short bf16x8;   // 8 bf16 = 4 VGPRs
typedef __attribute__((ext_vector_type(4))) float f32x4;

#define QSCALE 0.18033688011112042f   // (1/sqrt(64)) * log2(e)

static __device__ __forceinline__ f32x4 mfma_bf16(bf16x8 a, bf16x8 b, f32x4 c) {
    return __builtin_amdgcn_mfma_f32_16x16x32_bf16(a, b, c, 0, 0, 0);
}

static __device__ __forceinline__ void gld_lds16(const void* g, void* s) {
    __builtin_amdgcn_global_load_lds(
        (const __attribute__((address_space(1))) unsigned int*)g,
        (__attribute__((address_space(3))) unsigned int*)s,
        16, 0, 0);
}

// pack two fp32 -> bf16x2 (round-half-up), 3 VALU ops
static __device__ __forceinline__ unsigned int pk_bf16(float lo, float hi) {
    unsigned int ul = __builtin_bit_cast(unsigned int, lo) + 0x8000u;
    unsigned int uh = __builtin_bit_cast(unsigned int, hi) + 0x8000u;
    return __builtin_amdgcn_perm(uh, ul, 0x07060302u);   // {ul.hi16, uh.hi16}
}

// ---------------- fused prep: cast x + transpose both weights ----------------
// wqkvT row' = which*1024 + h*64 + dk (QSCALE folded into which==0 rows)
__global__ void prep_kernel(const float* __restrict__ x, bf16* __restrict__ xb,
                            const float* __restrict__ wqkv, bf16* __restrict__ wqkvT,
                            const float* __restrict__ wo, bf16* __restrict__ woT) {
    __shared__ float tile[32][33];
    int blk = blockIdx.x;
    if (blk < 4096) {
        int i = blk * 256 + threadIdx.x;
        float4 f = reinterpret_cast<const float4*>(x)[i];
        xb[4*i+0] = __float2bfloat16(f.x);
        xb[4*i+1] = __float2bfloat16(f.y);
        xb[4*i+2] = __float2bfloat16(f.z);
        xb[4*i+3] = __float2bfloat16(f.w);
        return;
    }
    int xo = threadIdx.x & 31, yo = threadIdx.x >> 5;   // (32,8)
    if (blk < 7168) {
        int idx = blk - 4096;
        int c0 = (idx % 96) * 32, r0 = (idx / 96) * 32;
#pragma unroll
        for (int i = 0; i < 32; i += 8)
            tile[yo + i][xo] = wqkv[(size_t)(r0 + yo + i) * 3072 + c0 + xo];
        __syncthreads();
#pragma unroll
        for (int i = 0; i < 32; i += 8) {
            int c = c0 + yo + i;
            int hh = c / 192, rem = c - hh * 192;
            int which = rem >> 6, dk = rem & 63;
            int rowp = which * 1024 + hh * 64 + dk;
            float sc = (which == 0) ? QSCALE : 1.0f;
            wqkvT[(size_t)rowp * 1024 + r0 + xo] = __float2bfloat16(tile[xo][yo + i] * sc);
        }
    } else {
        int idx = blk - 7168;
        int c0 = (idx & 31) * 32, r0 = (idx >> 5) * 32;
#pragma unroll
        for (int i = 0; i < 32; i += 8)
            tile[yo + i][xo] = wo[(size_t)(r0 + yo + i) * 1024 + c0 + xo];
        __syncthreads();
#pragma unroll
        for (int i = 0; i < 32; i += 8)
            woT[(size_t)(c0 + yo + i) * 1024 + r0 + xo] = __float2bfloat16(tile[xo][yo + i]);
    }
}

// ---------------- GEMM: C[M,N] = A[M,K] @ Bt[N,K]^T  (bf16 in, fp32 acc) ----------------
// EPI=0 (QKV, TM=128, permuted weights): bn<16 -> Q/K stores; bn>=16 -> V path:
//   in-LDS 128x128 transpose (XOR-swizzled 8B units over As+Bs) then coalesced
//   V^T store with attn kpos-permutation applied.
// EPI=1: out GEMM, fused bias + (gamma+1).
template <int EPI, int TM, int MINW>
__global__ __launch_bounds__(256, MINW)
void gemm_bt_kernel(const bf16* __restrict__ A, const bf16* __restrict__ Bt,
                    int M, int N, int K,
                    const float* __restrict__ bias, const float* __restrict__ gamma,
                    bf16* __restrict__ Qout, bf16* __restrict__ Kout, bf16* __restrict__ Vout,
                    float* __restrict__ Cout) {
    constexpr int MI = TM / 32;
    constexpr int CA = TM / 32;
    __shared__ __align__(16) bf16 smem[TM * 64 + 128 * 64];
    bf16* As = smem;
    bf16* Bs = smem + TM * 64;

    const int tid  = threadIdx.x;
    const int wave = tid >> 6, lane = tid & 63;
    const int quad = lane >> 4, l16 = lane & 15;
    const int wr = wave >> 1, wc = wave & 1;
    const int bm = blockIdx.y, bn = blockIdx.x;

    f32x4 acc[MI][4] = {};

    const int crow = lane >> 3;
    const int sblk = (lane & 7) ^ (crow & 7);
    const bf16* gA[CA]; const bf16* gB[4]; bf16* lA[CA]; bf16* lB[4];
#pragma unroll
    for (int c = 0; c < CA; ++c) {
        int ch = wave * CA + c;
        gA[c] = A + (size_t)(bm * TM + ch * 8 + crow) * K + sblk * 8;
        lA[c] = As + ch * 512 + lane * 8;
    }
#pragma unroll
    for (int c = 0; c < 4; ++c) {
        int ch = wave * 4 + c;
        gB[c] = Bt + (size_t)(bn * 128 + ch * 8 + crow) * K + sblk * 8;
        lB[c] = Bs + ch * 512 + lane * 8;
    }
    const int xr = l16 & 7;

    for (int k0 = 0; k0 < K; k0 += 64) {
#pragma unroll
        for (int c = 0; c < CA; ++c) gld_lds16(gA[c] + k0, lA[c]);
#pragma unroll
        for (int c = 0; c < 4; ++c) gld_lds16(gB[c] + k0, lB[c]);
        __syncthreads();
#pragma unroll
        for (int ks = 0; ks < 2; ++ks) {
            bf16x8 af[MI], bfr[4];
#pragma unroll
            for (int mi = 0; mi < MI; ++mi)
                af[mi] = *(const bf16x8*)(As + (wr * (TM/2) + mi * 16 + l16) * 64 + ((4 * ks + quad) ^ xr) * 8);
#pragma unroll
            for (int ni = 0; ni < 4; ++ni)
                bfr[ni] = *(const bf16x8*)(Bs + (wc * 64 + ni * 16 + l16) * 64 + ((4 * ks + quad) ^ xr) * 8);
#pragma unroll
            for (int mi = 0; mi < MI; ++mi)
#pragma unroll
                for (int ni = 0; ni < 4; ++ni)
                    acc[mi][ni] = mfma_bf16(af[mi], bfr[ni], acc[mi][ni]);
        }
        __syncthreads();
    }

    if (EPI == 0 && bn >= 16) {
        // ---- V path: in-LDS transpose + permuted coalesced V^T store ----
        __syncthreads();   // FIX(2): all waves' final MFMA frag reads done before Tu overwrite
        uint2* Tu = (uint2*)smem;   // 128 cols x 32 row-groups of 8B, XOR-swizzled
#pragma unroll
        for (int mi = 0; mi < MI; ++mi) {
#pragma unroll
            for (int ni = 0; ni < 4; ++ni) {
                int colL = wc * 64 + ni * 16 + l16;
                float bv = bias[(2 * (bn - 16) + wc) * 192 + 128 + (ni * 16 + l16)];
                uint2 pk;
                pk.x = pk_bf16(acc[mi][ni][0] + bv, acc[mi][ni][1] + bv);
                pk.y = pk_bf16(acc[mi][ni][2] + bv, acc[mi][ni][3] + bv);
                int rg = wr * 16 + mi * 4 + quad;
                Tu[colL * 32 + (rg ^ (colL & 31))] = pk;
            }
        }
        __syncthreads();
        const int sub = tid & 15, rbase = tid >> 4;
        const int cs = sub >> 3, aa = (sub >> 2) & 1, qq = sub & 3;
        const int g1 = cs * 16 + aa * 8 + qq;   // source row-group (jj 0..3)
        const int g2 = g1 + 4;                  // source row-group (jj 4..7)
        const int b = bm >> 4;
        const int s0 = (bm & 15) * 128;         // FIX(1): batch-local sequence base
#pragma unroll
        for (int j = 0; j < 8; ++j) {
            int rt = rbase + 16 * j;            // dk' 0..127
            int hh = 2 * (bn - 16) + (rt >> 6), dk = rt & 63;
            uint2 lo = Tu[rt * 32 + (g1 ^ (rt & 31))];
            uint2 hi = Tu[rt * 32 + (g2 ^ (rt & 31))];
            uint4 val; val.x = lo.x; val.y = lo.y; val.z = hi.x; val.w = hi.y;
            *(uint4*)(Vout + (((size_t)b * 16 + hh) * 64 + dk) * 2048 + s0 + sub * 8) = val;
        }
        return;
    }

#pragma unroll
    for (int mi = 0; mi < MI; ++mi) {
#pragma unroll
        for (int ni = 0; ni < 4; ++ni) {
            int col = bn * 128 + wc * 64 + ni * 16 + l16;
            if (EPI == 0) {
                int which = col >> 10, hh = (col >> 6) & 15, dk = col & 63;
                float bv = bias[hh * 192 + which * 64 + dk];
                if (which == 0) bv *= QSCALE;
                bf16* dst = which ? Kout : Qout;
#pragma unroll
                for (int r = 0; r < 4; ++r) {
                    int row = bm * TM + wr * (TM/2) + mi * 16 + quad * 4 + r;
                    int b = row >> 11, s = row & 2047;   // S = 2048
                    dst[(((size_t)b * 16 + hh) * 2048 + s) * 64 + dk] =
                        __float2bfloat16(acc[mi][ni][r] + bv);
                }
            } else {
                float g1 = gamma[col] + 1.0f, bv = bias[col];
#pragma unroll
                for (int r = 0; r < 4; ++r) {
                    int row = bm * TM + wr * (TM/2) + mi * 16 + quad * 4 + r;
                    Cout[(size_t)row * N + col] = g1 * (acc[mi][ni][r] + bv);
                }
            }
        }
    }
}

// ---------------- flash attention: exact R6 structure + pk_bf16 ----------------
// grid (S/128, B*H), block 128. Wave w owns q rows [q0+64w, +64) as m=0..3.
__global__ __launch_bounds__(128, 1)
void attn_kernel(const bf16* __restrict__ Qb, const bf16* __restrict__ Kb,
                 const bf16* __restrict__ Vtp, const int* __restrict__ mask,
                 bf16* __restrict__ Aout) {
    __shared__ __align__(16) bf16 Ks[2][64 * 64];   // [kpos][dk], XOR-swizzled blocks
    __shared__ __align__(16) bf16 Vs[2][64 * 64];   // [dk][kpos'], XOR-swizzled
    __shared__ float Biass[2][64];

    const int bh = blockIdx.y;
    const int b = bh >> 4, h = bh & 15;
    const int q0 = blockIdx.x * 128;
    const int tid = threadIdx.x;
    const int wave = tid >> 6, lane = tid & 63;
    const int quad = lane >> 4, l16 = lane & 15;
    const int xr = l16 & 7;

    bf16x8 aq[4][2];
#pragma unroll
    for (int m = 0; m < 4; ++m) {
        const bf16* qp = Qb + ((size_t)bh * 2048 + q0 + wave * 64 + m * 16 + l16) * 64;
        aq[m][0] = *(const bf16x8*)(qp + quad * 8);
        aq[m][1] = *(const bf16x8*)(qp + 32 + quad * 8);
    }

    bf16x8 ones;
#pragma unroll
    for (int j = 0; j < 8; ++j) ones[j] = (short)0x3F80;   // bf16 1.0

    f32x4 O[4][4] = {};
    f32x4 Lacc[4] = {};

    const int r8 = lane >> 3, b8 = lane & 7;
    const int srcb = b8 ^ r8;
    const bf16* gK = Kb  + ((size_t)bh * 2048 + wave * 8 + r8) * 64 + srcb * 8;
    const bf16* gV = Vtp + ((size_t)bh * 64 + wave * 8 + r8) * 2048 + srcb * 8;
    bf16* lK[2][4]; bf16* lV[2][4];
#pragma unroll
    for (int p = 0; p < 2; ++p)
#pragma unroll
        for (int c = 0; c < 4; ++c) {
            lK[p][c] = Ks[p] + c * 1024 + wave * 512 + lane * 8;
            lV[p][c] = Vs[p] + c * 1024 + wave * 512 + lane * 8;
        }

    int mreg = 0;
#pragma unroll
    for (int c = 0; c < 4; ++c) {
        gld_lds16(gK + c * 1024, lK[0][c]);
        gld_lds16(gV + (size_t)c * 32768, lV[0][c]);
    }
    if (tid < 64) {
        Biass[0][tid] = mask[b * 2048 + tid] ? -24.0f : -1e30f;
        mreg = mask[b * 2048 + 64 + tid];
    }

    for (int kt = 0; kt < 32; ++kt) {
        __syncthreads();
        const int cur = kt & 1, nxt = cur ^ 1;

        if (kt + 1 < 32) {
#pragma unroll
            for (int c = 0; c < 4; ++c) {
                gld_lds16(gK + (size_t)(kt + 1) * 4096 + c * 1024, lK[nxt][c]);
                gld_lds16(gV + (kt + 1) * 64 + (size_t)c * 32768, lV[nxt][c]);
            }
            if (tid < 64) Biass[nxt][tid] = mreg ? -24.0f : -1e30f;
        }
        if (kt + 2 < 32 && tid < 64) mreg = mask[b * 2048 + (kt + 2) * 64 + tid];

        f32x4 bias4[4];
        bf16x8 bk[4][2];
#pragma unroll
        for (int kt4 = 0; kt4 < 4; ++kt4) {
            bias4[kt4] = *(const f32x4*)(&Biass[cur][0] + kt4 * 16 + quad * 4);
            const bf16* kp = Ks[cur] + (kt4 * 16 + l16) * 64;
            bk[kt4][0] = *(const bf16x8*)(kp + (quad ^ xr) * 8);
            bk[kt4][1] = *(const bf16x8*)(kp + ((quad + 4) ^ xr) * 8);
        }
        bf16x8 bv8[2][4];
#pragma unroll
        for (int a = 0; a < 2; ++a)
#pragma unroll
            for (int nt = 0; nt < 4; ++nt)
                bv8[a][nt] = *(const bf16x8*)(Vs[cur] + (nt * 16 + l16) * 64 + ((a * 4 + quad) ^ xr) * 8);

#pragma unroll
        for (int m = 0; m < 4; ++m) {
            f32x4 sv[4];
#pragma unroll
            for (int kt4 = 0; kt4 < 4; ++kt4) {
                f32x4 c = {0.f, 0.f, 0.f, 0.f};
                c = mfma_bf16(bk[kt4][0], aq[m][0], c);
                c = mfma_bf16(bk[kt4][1], aq[m][1], c);
                sv[kt4] = c;
            }
            float p[4][4];
#pragma unroll
            for (int kt4 = 0; kt4 < 4; ++kt4)
#pragma unroll
                for (int r = 0; r < 4; ++r)
                    p[kt4][r] = __builtin_amdgcn_exp2f(sv[kt4][r] + bias4[kt4][r]);

#pragma unroll
            for (int a = 0; a < 2; ++a) {
                uint4 uv;
                uv.x = pk_bf16(p[2*a][0],   p[2*a][1]);
                uv.y = pk_bf16(p[2*a][2],   p[2*a][3]);
                uv.z = pk_bf16(p[2*a+1][0], p[2*a+1][1]);
                uv.w = pk_bf16(p[2*a+1][2], p[2*a+1][3]);
                bf16x8 pa = __builtin_bit_cast(bf16x8, uv);
                Lacc[m] = mfma_bf16(pa, ones, Lacc[m]);
#pragma unroll
                for (int nt = 0; nt < 4; ++nt)
                    O[m][nt] = mfma_bf16(pa, bv8[a][nt], O[m][nt]);
            }
        }
    }

#pragma unroll
    for (int m = 0; m < 4; ++m) {
        float inv[4];
#pragma unroll
        for (int r = 0; r < 4; ++r) inv[r] = __builtin_amdgcn_rcpf(Lacc[m][r]);
#pragma unroll
        for (int nt = 0; nt < 4; ++nt) {
#pragma unroll
            for (int r = 0; r < 4; ++r) {
                int row = q0 + wave * 64 + m * 16 + quad * 4 + r;
                Aout[((size_t)b * 2048 + row) * 1024 + h * 64 + nt * 16 + l16] =
                    __float2bfloat16(O[m][nt][r] * inv[r]);
            }
        }
    }
}

// ---------------- launcher ----------------
extern "C" void kernel_launch(void* const* d_in, const int* in_sizes, int n_in,
                              void* d_out, int out_size, void* d_ws, size_t ws_size,
                              hipStream_t stream) {
    const float* x     = (const float*)d_in[0];
    const float* gamma = (const float*)d_in[1];
    const int*   mask  = (const int*)d_in[2];
    const float* wqkv  = (const float*)d_in[3];
    const float* bqkv  = (const float*)d_in[4];
    const float* wo    = (const float*)d_in[5];
    const float* bo    = (const float*)d_in[6];
    float* out = (float*)d_out;

    char* ws = (char*)d_ws;
    const size_t MB = 1u << 20;
    bf16* xb    = (bf16*)(ws);            //  8 MB
    bf16* wqkvT = (bf16*)(ws + 8 * MB);   //  6 MB (which-major, QSCALE folded)
    bf16* woT   = (bf16*)(ws + 14 * MB);  //  2 MB
    bf16* Qb    = (bf16*)(ws + 16 * MB);  //  8 MB
    bf16* Kb    = (bf16*)(ws + 24 * MB);  //  8 MB
    bf16* Vt    = (bf16*)(ws + 32 * MB);  //  8 MB (V^T, kpos-permuted; written by GEMM)
    bf16* attn  = (bf16*)(ws + 40 * MB);  //  8 MB

    prep_kernel<<<8192, 256, 0, stream>>>(x, xb, wqkv, wqkvT, wo, woT);

    // QKV GEMM: [4096,1024] x [1024,3072]; V blocks write Vt directly
    gemm_bt_kernel<0, 128, 3><<<dim3(24, 32), 256, 0, stream>>>(
        xb, wqkvT, 4096, 3072, 1024, bqkv, nullptr, Qb, Kb, Vt, nullptr);

    // attention: grid (S/128, B*H), 128-thread blocks
    attn_kernel<<<dim3(16, 32), 128, 0, stream>>>(Qb, Kb, Vt, mask, attn);

    // out GEMM: [4096,1024] x [1024,1024]
    gemm_bt_kernel<1, 64, 4><<<dim3(8, 64), 256, 0, stream>>>(
        attn, woT, 4096, 1024, 1024, bo, gamma, nullptr, nullptr, nullptr, out);
}